// Round 3
// baseline (361.875 us; speedup 1.0000x reference)
//
#include <hip/hip_runtime.h>

// CenterLoss: mean((input_x - target_x[labels])^2)
// N=131072 rows, FEAT=512, NCLASS=1000. All f32. Output: single f32 scalar.
//
// R2 analysis: kernel ~100us (latency-bound, ~2.7 TB/s). Fixes:
//  - 4x unroll w/ independent addresses -> 8 loads in flight per thread
//  - int32 chunk indices (16.7M < 2^31)
//  - labels wave-uniform (64 aligned chunks/wave = same row) -> readfirstlane
//  - no nt hint: restore-copy leaves x L3-resident, let loads hit IC

#define NROWS   131072
#define FEAT    512
#define CPR     128                          // float4 chunks per row
constexpr int BLOCKS  = 2048;                // 8 blocks/CU * 256 CU
constexpr int THREADS = 256;
constexpr int STRIDE  = BLOCKS * THREADS;    // 524288
constexpr int TOTAL   = NROWS * CPR;         // 16,777,216
constexpr int ITERS   = TOTAL / STRIDE;      // 32 (exact)
constexpr int UNROLL  = 4;

typedef float f32x4 __attribute__((ext_vector_type(4)));

__global__ __launch_bounds__(THREADS) void center_loss_partial(
        const f32x4* __restrict__ x,         // [NROWS * 128]
        const int*   __restrict__ labels,    // [NROWS]
        const f32x4* __restrict__ centers,   // [NCLASS * 128]
        float*       __restrict__ partial)   // [BLOCKS]
{
    const int tid = threadIdx.x;
    int c = blockIdx.x * THREADS + tid;

    float acc0 = 0.f, acc1 = 0.f, acc2 = 0.f, acc3 = 0.f;
#pragma unroll 1
    for (int it = 0; it < ITERS / UNROLL; ++it) {
        const int c0 = c;
        const int c1 = c +     STRIDE;
        const int c2 = c + 2 * STRIDE;
        const int c3 = c + 3 * STRIDE;
        // wave spans 64 aligned chunks -> one row -> label wave-uniform
        const int lab0 = __builtin_amdgcn_readfirstlane(labels[c0 >> 7]);
        const int lab1 = __builtin_amdgcn_readfirstlane(labels[c1 >> 7]);
        const int lab2 = __builtin_amdgcn_readfirstlane(labels[c2 >> 7]);
        const int lab3 = __builtin_amdgcn_readfirstlane(labels[c3 >> 7]);
        const f32x4 xv0 = x[c0];
        const f32x4 xv1 = x[c1];
        const f32x4 xv2 = x[c2];
        const f32x4 xv3 = x[c3];
        const f32x4 cv0 = centers[lab0 * CPR + (c0 & (CPR - 1))];
        const f32x4 cv1 = centers[lab1 * CPR + (c1 & (CPR - 1))];
        const f32x4 cv2 = centers[lab2 * CPR + (c2 & (CPR - 1))];
        const f32x4 cv3 = centers[lab3 * CPR + (c3 & (CPR - 1))];

        f32x4 d0 = xv0 - cv0;
        f32x4 d1 = xv1 - cv1;
        f32x4 d2 = xv2 - cv2;
        f32x4 d3 = xv3 - cv3;
        acc0 += d0.x * d0.x + d0.y * d0.y + d0.z * d0.z + d0.w * d0.w;
        acc1 += d1.x * d1.x + d1.y * d1.y + d1.z * d1.z + d1.w * d1.w;
        acc2 += d2.x * d2.x + d2.y * d2.y + d2.z * d2.z + d2.w * d2.w;
        acc3 += d3.x * d3.x + d3.y * d3.y + d3.z * d3.z + d3.w * d3.w;

        c += UNROLL * STRIDE;
    }

    float acc = (acc0 + acc1) + (acc2 + acc3);

    // wave (64-lane) butterfly reduce
    for (int off = 32; off > 0; off >>= 1)
        acc += __shfl_down(acc, off, 64);

    __shared__ float s[THREADS / 64];
    const int lane = tid & 63;
    const int wave = tid >> 6;
    if (lane == 0) s[wave] = acc;
    __syncthreads();
    if (tid == 0)
        partial[blockIdx.x] = s[0] + s[1] + s[2] + s[3];
}

__global__ __launch_bounds__(256) void center_loss_final(
        const float* __restrict__ partial,   // [BLOCKS]
        float*       __restrict__ out)       // [1]
{
    const int tid = threadIdx.x;
    double acc = 0.0;
    for (int i = tid; i < BLOCKS; i += 256)
        acc += (double)partial[i];

    for (int off = 32; off > 0; off >>= 1)
        acc += __shfl_down(acc, off, 64);

    __shared__ double s[4];
    const int lane = tid & 63;
    const int wave = tid >> 6;
    if (lane == 0) s[wave] = acc;
    __syncthreads();
    if (tid == 0) {
        const double total = s[0] + s[1] + s[2] + s[3];
        out[0] = (float)(total / ((double)NROWS * (double)FEAT));
    }
}

extern "C" void kernel_launch(void* const* d_in, const int* in_sizes, int n_in,
                              void* d_out, int out_size, void* d_ws, size_t ws_size,
                              hipStream_t stream) {
    const f32x4* x       = (const f32x4*)d_in[0];  // input_x  [131072,512] f32
    const int*   labels  = (const int*)  d_in[1];  // labels   [131072] i32
    const f32x4* centers = (const f32x4*)d_in[2];  // target_x [1000,512] f32
    float*       out     = (float*)d_out;
    float*       partial = (float*)d_ws;           // BLOCKS floats (8 KiB)

    center_loss_partial<<<BLOCKS, THREADS, 0, stream>>>(x, labels, centers, partial);
    center_loss_final<<<1, 256, 0, stream>>>(partial, out);
}